// Round 4
// baseline (289.621 us; speedup 1.0000x reference)
//
#include <hip/hip_runtime.h>

// Problem constants: B=2, S=2048, IN=4096, OUT=4096, RANK=8, LORA_R=16
#define M_DIM 4096
#define IN_DIM 4096
#define OUT_DIM 4096
#define RANK 8
#define LORA_R 16
#define LORA_SCALING 1.0f

typedef __bf16 bf16;
typedef bf16  bf16x4 __attribute__((ext_vector_type(4)));
typedef bf16  bf16x8 __attribute__((ext_vector_type(8)));
typedef float f32x4  __attribute__((ext_vector_type(4)));

// -------------------------------------------------------------------------
// Kernel 1 (fused): blocks [0,2048) fold weight; blocks [2048,4096) cast x.
// UNCHANGED.
// -------------------------------------------------------------------------
#define OG 8
__global__ __launch_bounds__(256) void prep_fused(
    const float* __restrict__ weight, const float* __restrict__ scale_A,
    const float* __restrict__ scale_B, const float* __restrict__ g,
    const float* __restrict__ lora_A, const float* __restrict__ lora_B,
    const float* __restrict__ x, bf16* __restrict__ wt, bf16* __restrict__ xb)
{
    const int t = threadIdx.x;
    if (blockIdx.x < 2048) {
        __shared__ float s_sa[OG][RANK];
        __shared__ float s_lb[OG][LORA_R];
        const int o0 = (blockIdx.x >> 2) * OG;
        if (t < OG * RANK) {
            int r8 = t / RANK, k = t % RANK;
            s_sa[r8][k] = scale_A[(o0 + r8) * RANK + k] * g[k];
        }
        if (t < OG * LORA_R) {
            int r8 = t / LORA_R, r = t % LORA_R;
            s_lb[r8][r] = lora_B[(o0 + r8) * LORA_R + r] * LORA_SCALING;
        }
        __syncthreads();

        const int i0 = ((blockIdx.x & 3) * 256 + t) * 4;

        f32x4 acc[OG];
#pragma unroll
        for (int r8 = 0; r8 < OG; ++r8) acc[r8] = {0.f, 0.f, 0.f, 0.f};
#pragma unroll
        for (int k = 0; k < RANK; ++k) {
            f32x4 sbk = *(const f32x4*)(scale_B + k * IN_DIM + i0);
#pragma unroll
            for (int r8 = 0; r8 < OG; ++r8) acc[r8] += s_sa[r8][k] * sbk;
        }
#pragma unroll
        for (int r8 = 0; r8 < OG; ++r8) {
            f32x4 wv = *(const f32x4*)(weight + (size_t)(o0 + r8) * IN_DIM + i0);
            acc[r8] *= wv;
        }
#pragma unroll
        for (int r = 0; r < LORA_R; ++r) {
            f32x4 lak = *(const f32x4*)(lora_A + r * IN_DIM + i0);
#pragma unroll
            for (int r8 = 0; r8 < OG; ++r8) acc[r8] += s_lb[r8][r] * lak;
        }
#pragma unroll
        for (int r8 = 0; r8 < OG; ++r8) {
            bf16x4 h = { (bf16)acc[r8][0], (bf16)acc[r8][1],
                         (bf16)acc[r8][2], (bf16)acc[r8][3] };
            *(bf16x4*)(wt + (size_t)(o0 + r8) * IN_DIM + i0) = h;
        }
    } else {
        const int n4  = (M_DIM * IN_DIM) / 4;
        int idx    = (blockIdx.x - 2048) * 256 + t;
        int stride = 2048 * 256;
        for (int i = idx; i < n4; i += stride) {
            f32x4 v = *(const f32x4*)(x + (size_t)i * 4);
            bf16x4 h = { (bf16)v[0], (bf16)v[1], (bf16)v[2], (bf16)v[3] };
            *(bf16x4*)(xb + (size_t)i * 4) = h;
        }
    }
}

// -------------------------------------------------------------------------
// Kernel 2: 256x256 tile, BK=64, 8 waves (2Mx4N), MFMA 16x16x32,
// LDS halves [128 rows][128B], swizzle sigma(row,c) = c ^ (row&7)
// (R3: conflicts 1.52e7 -> 5.2e5, free).
//
// R4 change (ONLY): de-lockstep the phase. R3's per-phase
// {reads -> BARRIER -> lgkmcnt(0) -> MFMA -> vmcnt -> BARRIER} ran LDS
// service and MFMA serially (measured: 4688 cyc/K-tile ~= 2457 MFMA +
// 2048 LDS + sync; MfmaUtil 48%). Now: {reads -> STAGE -> MFMA (compiler
// emits fine-grained per-use lgkmcnt) -> vmcnt(4) -> BARRIER}. One
// barrier per phase. Wave k starts MFMA when ITS frags land while later
// waves' reads are still served -> LDS hides under MFMA via stagger.
//
// Correctness (audited): during tile t ALL reads hit buffer p and ALL
// stages write buffer q != p -> no intra-tile hazard; the open barrier
// was pure lockstep. Cross-tile visibility unchanged: per-wave vmcnt(4)
// before each close barrier keeps the R3 ledger (stage of X-half landed
// & globally visible before any wave's reads of it next tile). Stale-
// read-vs-overwrite: a wave's p-reads retire before its own MFMA
// (data dep) which precedes its barrier; stages into p issue only after
// that barrier.
//
// LDS map (bytes), buffer p at p*65536:
//   A-half h: p*65536 + h*16384,  B-half h: p*65536 + 32768 + h*16384
// Phases = global C-quadrants: ph1 (0,0), ph2 (0,1), ph3 (1,1), ph4 (1,0).
// Stage schedule (tile t+1): ph1: A-h0, ph2: B-h0, ph3: B-h1, ph4: A-h1.
// Uniform vmcnt(4) at every phase close (4 loads in flight, never 0).
// -------------------------------------------------------------------------
#define BM 256
#define BN 256
#define BK 64

__device__ __forceinline__ void gload16(const bf16* g, bf16* l) {
    __builtin_amdgcn_global_load_lds(
        (const __attribute__((address_space(1))) void*)g,
        (__attribute__((address_space(3))) void*)l,
        16, 0, 0);
}

#define BARRIER()    __builtin_amdgcn_s_barrier()
#define WAIT_VM(n)   asm volatile("s_waitcnt vmcnt(" #n ")" ::: "memory")

__device__ __forceinline__ void load_af(bf16x8 (&aF)[4][2], const char* aB,
                                        int off, int s0, int s1) {
#pragma unroll
    for (int r = 0; r < 4; ++r) {
        aF[r][0] = *(const bf16x8*)(aB + off + r * 2048 + s0);
        aF[r][1] = *(const bf16x8*)(aB + off + r * 2048 + s1);
    }
}
__device__ __forceinline__ void load_bf(bf16x8 (&bF)[2][2], const char* bB,
                                        int off, int s0, int s1) {
#pragma unroll
    for (int n = 0; n < 2; ++n) {
        bF[n][0] = *(const bf16x8*)(bB + off + n * 2048 + s0);
        bF[n][1] = *(const bf16x8*)(bB + off + n * 2048 + s1);
    }
}

template<int QM, int QN>
__device__ __forceinline__ void mfma_quad(f32x4 (&acc)[2][2][4][2],
                                          const bf16x8 (&aF)[4][2],
                                          const bf16x8 (&bF)[2][2]) {
#pragma unroll
    for (int ks = 0; ks < 2; ++ks)
#pragma unroll
        for (int r = 0; r < 4; ++r)
#pragma unroll
            for (int n = 0; n < 2; ++n)
                acc[QM][QN][r][n] = __builtin_amdgcn_mfma_f32_16x16x32_bf16(
                    aF[r][ks], bF[n][ks], acc[QM][QN][r][n], 0, 0, 0);
}

__global__ __launch_bounds__(512, 2) void gemm_bt(
    const bf16* __restrict__ A,   // [4096,4096] bf16 row-major (x)
    const bf16* __restrict__ Bw,  // [4096,4096] bf16 row-major (W_eff, B^T)
    float* __restrict__ C)        // [4096,4096] fp32 row-major
{
    __shared__ __align__(16) char smem[131072];

    const int t  = threadIdx.x;
    const int w  = t >> 6;        // wave 0..7
    const int l  = t & 63;
    const int wm = w >> 2;        // 0..1 -> wave M offset within quadrant: wm*64
    const int wn = w & 3;         // 0..3 -> wave N offset within quadrant: wn*32

    // XCD-compact block mapping: 256 blocks = 8 XCDs x (4M x 8N) tile chunk.
    const int bid = blockIdx.x;
    const int xcd = bid & 7;
    const int loc = bid >> 3;                      // 0..31
    const int mt  = (xcd & 3) * 4 + (loc >> 3);    // 0..15
    const int nt  = (xcd >> 2) * 8 + (loc & 7);    // 0..15
    const int m0  = mt * BM;
    const int n0  = nt * BN;

    // ---- staging (per lane): wave w covers rows w*8 + (l>>3) (+64 for 2nd
    // gload). Pre-swizzled global source chunk: (l&7) ^ ((l>>3)&7).
    const int scol = 8 * ((l & 7) ^ ((l >> 3) & 7));
    const bf16* gAs = A  + (size_t)(m0 + w * 8 + (l >> 3)) * IN_DIM + scol;
    const bf16* gBs = Bw + (size_t)(n0 + w * 8 + (l >> 3)) * IN_DIM + scol;

#define STAGEH(gbase, kc, dstOff) do {                                        \
        gload16((gbase) + (kc),                                               \
                (bf16*)(smem + (dstOff) + (w << 10)));                        \
        gload16((gbase) + (kc) + (size_t)64 * IN_DIM,                         \
                (bf16*)(smem + (dstOff) + 8192 + (w << 10)));                 \
    } while (0)

    // ---- ds_read slot offsets: slot(ks) = (ks*4 + (l>>4)) ^ (l&7).
    const int fr  = l & 15;
    const int sA0 = (((l >> 4) & 3) ^ (l & 7)) << 4;
    const int sA1 = ((4 | ((l >> 4) & 3)) ^ (l & 7)) << 4;
    const char* aB = smem + wm * 8192 + fr * 128;            // + po + QM*16384
    const char* bB = smem + 32768 + wn * 4096 + fr * 128;    // + po + QN*16384

    f32x4 acc[2][2][4][2] = {};
    bf16x8 aF[4][2], bF[2][2];

    // ---- prologue: tile 0's halves in deadline order; keep last 4 in flight.
    STAGEH(gAs, 0, 0);                                   // A-h0(0)
    STAGEH(gBs, 0, 32768);                               // B-h0(0)
    STAGEH(gBs + (size_t)128 * IN_DIM, 0, 49152);        // B-h1(0)
    STAGEH(gAs + (size_t)128 * IN_DIM, 0, 16384);        // A-h1(0)
    WAIT_VM(4);
    BARRIER();

#pragma unroll 2
    for (int kt = 0; kt < 64; ++kt) {
        const int po  = (kt & 1) << 16;
        const int qo  = po ^ 65536;
        const int kcn = (kt + 1 < 64) ? (kt + 1) * BK : 0;   // clamped (bf16 cols)

        // ===== phase 1: quadrant (0,0) =====
        load_af(aF, aB, po, sA0, sA1);
        load_bf(bF, bB, po, sA0, sA1);
        STAGEH(gAs, kcn, qo);                            // A-h0(t+1)
        __builtin_amdgcn_s_setprio(1);
        mfma_quad<0, 0>(acc, aF, bF);
        __builtin_amdgcn_s_setprio(0);
        WAIT_VM(4);
        BARRIER();

        // ===== phase 2: quadrant (0,1) — A-frags reused =====
        load_bf(bF, bB, po + 16384, sA0, sA1);
        STAGEH(gBs, kcn, qo + 32768);                    // B-h0(t+1)
        __builtin_amdgcn_s_setprio(1);
        mfma_quad<0, 1>(acc, aF, bF);
        __builtin_amdgcn_s_setprio(0);
        WAIT_VM(4);
        BARRIER();

        // ===== phase 3: quadrant (1,1) — B-frags reused =====
        load_af(aF, aB, po + 16384, sA0, sA1);
        STAGEH(gBs + (size_t)128 * IN_DIM, kcn, qo + 49152);   // B-h1(t+1)
        __builtin_amdgcn_s_setprio(1);
        mfma_quad<1, 1>(acc, aF, bF);
        __builtin_amdgcn_s_setprio(0);
        WAIT_VM(4);
        BARRIER();

        // ===== phase 4: quadrant (1,0) — A-frags reused =====
        load_bf(bF, bB, po, sA0, sA1);
        STAGEH(gAs + (size_t)128 * IN_DIM, kcn, qo + 16384);   // A-h1(t+1)
        __builtin_amdgcn_s_setprio(1);
        mfma_quad<1, 0>(acc, aF, bF);
        __builtin_amdgcn_s_setprio(0);
        WAIT_VM(4);
        BARRIER();
    }

    // ---- epilogue: drain, then per-wave LDS transpose (stride 33) ----
    asm volatile("s_waitcnt vmcnt(0) lgkmcnt(0)" ::: "memory");
    BARRIER();
    float* sE = (float*)(void*)smem + w * (64 * 33);   // 8448B/wave * 8 = 67.6KB
    const int er = l >> 4;        // 0..3
    const int ec = l & 15;
#pragma unroll
    for (int QM = 0; QM < 2; ++QM)
#pragma unroll
        for (int QN = 0; QN < 2; ++QN) {
            // C/D layout (m89/m91): col = l&15, row = (l>>4)*4 + j
#pragma unroll
            for (int r = 0; r < 4; ++r)
#pragma unroll
                for (int n = 0; n < 2; ++n)
#pragma unroll
                    for (int j = 0; j < 4; ++j)
                        sE[(r * 16 + er * 4 + j) * 33 + n * 16 + ec] =
                            acc[QM][QN][r][n][j];
#pragma unroll
            for (int q = 0; q < 8; ++q) {
                int r2 = q * 8 + (l >> 3);
                int c2 = (l & 7) * 4;
                f32x4 v = { sE[r2 * 33 + c2],     sE[r2 * 33 + c2 + 1],
                            sE[r2 * 33 + c2 + 2], sE[r2 * 33 + c2 + 3] };
                *(f32x4*)(C + (size_t)(m0 + QM * 128 + wm * 64 + r2) * OUT_DIM
                            + (n0 + QN * 128 + wn * 32 + c2)) = v;
            }
        }
}

// -------------------------------------------------------------------------
extern "C" void kernel_launch(void* const* d_in, const int* in_sizes, int n_in,
                              void* d_out, int out_size, void* d_ws, size_t ws_size,
                              hipStream_t stream) {
    (void)in_sizes; (void)n_in; (void)out_size; (void)ws_size;
    const float* x        = (const float*)d_in[0];
    const float* weight   = (const float*)d_in[1];
    const float* scale_A  = (const float*)d_in[2];
    const float* scale_B  = (const float*)d_in[3];
    const float* g        = (const float*)d_in[4];
    const float* lora_A   = (const float*)d_in[5];
    const float* lora_B   = (const float*)d_in[6];
    float* out = (float*)d_out;

    bf16* xb = (bf16*)d_ws;
    bf16* wt = (bf16*)((char*)d_ws + (size_t)M_DIM * IN_DIM * sizeof(bf16));

    prep_fused<<<4096, 256, 0, stream>>>(weight, scale_A, scale_B, g,
                                         lora_A, lora_B, x, wt, xb);

    gemm_bt<<<(M_DIM / BM) * (OUT_DIM / BN), 512, 0, stream>>>(xb, wt, out);
}

// Round 5
// 288.764 us; speedup vs baseline: 1.0030x; 1.0030x over previous
//
#include <hip/hip_runtime.h>

// Problem constants: B=2, S=2048, IN=4096, OUT=4096, RANK=8, LORA_R=16
#define M_DIM 4096
#define IN_DIM 4096
#define OUT_DIM 4096
#define RANK 8
#define LORA_R 16
#define LORA_SCALING 1.0f

typedef __bf16 bf16;
typedef bf16  bf16x4 __attribute__((ext_vector_type(4)));
typedef bf16  bf16x8 __attribute__((ext_vector_type(8)));
typedef float f32x4  __attribute__((ext_vector_type(4)));

// -------------------------------------------------------------------------
// Kernel 1 (fused): blocks [0,2048) fold weight; blocks [2048,4096) cast x.
// UNCHANGED.
// -------------------------------------------------------------------------
#define OG 8
__global__ __launch_bounds__(256) void prep_fused(
    const float* __restrict__ weight, const float* __restrict__ scale_A,
    const float* __restrict__ scale_B, const float* __restrict__ g,
    const float* __restrict__ lora_A, const float* __restrict__ lora_B,
    const float* __restrict__ x, bf16* __restrict__ wt, bf16* __restrict__ xb)
{
    const int t = threadIdx.x;
    if (blockIdx.x < 2048) {
        __shared__ float s_sa[OG][RANK];
        __shared__ float s_lb[OG][LORA_R];
        const int o0 = (blockIdx.x >> 2) * OG;
        if (t < OG * RANK) {
            int r8 = t / RANK, k = t % RANK;
            s_sa[r8][k] = scale_A[(o0 + r8) * RANK + k] * g[k];
        }
        if (t < OG * LORA_R) {
            int r8 = t / LORA_R, r = t % LORA_R;
            s_lb[r8][r] = lora_B[(o0 + r8) * LORA_R + r] * LORA_SCALING;
        }
        __syncthreads();

        const int i0 = ((blockIdx.x & 3) * 256 + t) * 4;

        f32x4 acc[OG];
#pragma unroll
        for (int r8 = 0; r8 < OG; ++r8) acc[r8] = {0.f, 0.f, 0.f, 0.f};
#pragma unroll
        for (int k = 0; k < RANK; ++k) {
            f32x4 sbk = *(const f32x4*)(scale_B + k * IN_DIM + i0);
#pragma unroll
            for (int r8 = 0; r8 < OG; ++r8) acc[r8] += s_sa[r8][k] * sbk;
        }
#pragma unroll
        for (int r8 = 0; r8 < OG; ++r8) {
            f32x4 wv = *(const f32x4*)(weight + (size_t)(o0 + r8) * IN_DIM + i0);
            acc[r8] *= wv;
        }
#pragma unroll
        for (int r = 0; r < LORA_R; ++r) {
            f32x4 lak = *(const f32x4*)(lora_A + r * IN_DIM + i0);
#pragma unroll
            for (int r8 = 0; r8 < OG; ++r8) acc[r8] += s_lb[r8][r] * lak;
        }
#pragma unroll
        for (int r8 = 0; r8 < OG; ++r8) {
            bf16x4 h = { (bf16)acc[r8][0], (bf16)acc[r8][1],
                         (bf16)acc[r8][2], (bf16)acc[r8][3] };
            *(bf16x4*)(wt + (size_t)(o0 + r8) * IN_DIM + i0) = h;
        }
    } else {
        const int n4  = (M_DIM * IN_DIM) / 4;
        int idx    = (blockIdx.x - 2048) * 256 + t;
        int stride = 2048 * 256;
        for (int i = idx; i < n4; i += stride) {
            f32x4 v = *(const f32x4*)(x + (size_t)i * 4);
            bf16x4 h = { (bf16)v[0], (bf16)v[1], (bf16)v[2], (bf16)v[3] };
            *(bf16x4*)(xb + (size_t)i * 4) = h;
        }
    }
}

// -------------------------------------------------------------------------
// Kernel 2: 256x256 tile, BK=64, 8 waves (2Mx4N), MFMA 16x16x32,
// LDS halves [128 rows][128B], swizzle sigma(row,c) = c ^ (row&7)
// (conflicts 5.2e5 ~ free). Single barrier per phase (R4).
//
// R5 change (ONLY): m201 deep-prefetch ledger. Region liveness in buffer
// p during tile t: A-h0 dies ph1(t); B-h0 dies ph4(t) (re-read); B-h1 and
// A-h1 die ph3(t). Stage schedule (into dead regions only, each issue
// barrier-separated from the region's last reader):
//   ph1(t): B-h0(t+1) -> q.B-h0   [q.B-h0 died ph4(t-1)]
//   ph2(t): A-h0(t+2) -> p.A-h0   [died ph1(t)]
//   ph3(t): (no stage)
//   ph4(t): A-h1(t+2) -> p.A-h1, B-h1(t+2) -> p.B-h1  [died ph3(t)]
// ONE vmcnt(6) per K-tile at ph4 close (was 4x vmcnt(4)). In-order drain:
// newest 6 loads at ph4(t) close = {A-h0,A-h1,B-h1}(t+2); B-h0(t+1)
// [ph1(t)] and everything older (all of t+1) drained => tile t+1 fully
// resident at ph1(t+1) open. Prefetch runs 1.5-2 tiles ahead, 3 STAGEHs
// in flight -- the m201 invariant ("3 half-tiles in flight, vmcnt once
// per K-tile, never 0").
// Tail: kc clamped stages land only in dead regions; epilogue does
// vmcnt(0)+barrier before smem reuse.
//
// Reads per tile (unchanged): ph1: A-h0(8)+B-h0(4); ph2: B-h1(4);
// ph3: A-h1(8); ph4: B-h0 re-read(4).  Phases = C-quadrants
// (0,0),(0,1),(1,1),(1,0); A-frags reused ph1->ph2 and ph3->ph4.
// -------------------------------------------------------------------------
#define BM 256
#define BN 256
#define BK 64

__device__ __forceinline__ void gload16(const bf16* g, bf16* l) {
    __builtin_amdgcn_global_load_lds(
        (const __attribute__((address_space(1))) void*)g,
        (__attribute__((address_space(3))) void*)l,
        16, 0, 0);
}

#define BARRIER()    __builtin_amdgcn_s_barrier()
#define WAIT_VM(n)   asm volatile("s_waitcnt vmcnt(" #n ")" ::: "memory")

__device__ __forceinline__ void load_af(bf16x8 (&aF)[4][2], const char* aB,
                                        int off, int s0, int s1) {
#pragma unroll
    for (int r = 0; r < 4; ++r) {
        aF[r][0] = *(const bf16x8*)(aB + off + r * 2048 + s0);
        aF[r][1] = *(const bf16x8*)(aB + off + r * 2048 + s1);
    }
}
__device__ __forceinline__ void load_bf(bf16x8 (&bF)[2][2], const char* bB,
                                        int off, int s0, int s1) {
#pragma unroll
    for (int n = 0; n < 2; ++n) {
        bF[n][0] = *(const bf16x8*)(bB + off + n * 2048 + s0);
        bF[n][1] = *(const bf16x8*)(bB + off + n * 2048 + s1);
    }
}

template<int QM, int QN>
__device__ __forceinline__ void mfma_quad(f32x4 (&acc)[2][2][4][2],
                                          const bf16x8 (&aF)[4][2],
                                          const bf16x8 (&bF)[2][2]) {
#pragma unroll
    for (int ks = 0; ks < 2; ++ks)
#pragma unroll
        for (int r = 0; r < 4; ++r)
#pragma unroll
            for (int n = 0; n < 2; ++n)
                acc[QM][QN][r][n] = __builtin_amdgcn_mfma_f32_16x16x32_bf16(
                    aF[r][ks], bF[n][ks], acc[QM][QN][r][n], 0, 0, 0);
}

__global__ __launch_bounds__(512, 2) void gemm_bt(
    const bf16* __restrict__ A,   // [4096,4096] bf16 row-major (x)
    const bf16* __restrict__ Bw,  // [4096,4096] bf16 row-major (W_eff, B^T)
    float* __restrict__ C)        // [4096,4096] fp32 row-major
{
    __shared__ __align__(16) char smem[131072];

    const int t  = threadIdx.x;
    const int w  = t >> 6;        // wave 0..7
    const int l  = t & 63;
    const int wm = w >> 2;        // 0..1 -> wave M offset within quadrant: wm*64
    const int wn = w & 3;         // 0..3 -> wave N offset within quadrant: wn*32

    // XCD-compact block mapping: 256 blocks = 8 XCDs x (4M x 8N) tile chunk.
    const int bid = blockIdx.x;
    const int xcd = bid & 7;
    const int loc = bid >> 3;                      // 0..31
    const int mt  = (xcd & 3) * 4 + (loc >> 3);    // 0..15
    const int nt  = (xcd >> 2) * 8 + (loc & 7);    // 0..15
    const int m0  = mt * BM;
    const int n0  = nt * BN;

    // ---- staging (per lane): wave w covers rows w*8 + (l>>3) (+64 for 2nd
    // gload). Pre-swizzled global source chunk: (l&7) ^ ((l>>3)&7).
    const int scol = 8 * ((l & 7) ^ ((l >> 3) & 7));
    const bf16* gAs = A  + (size_t)(m0 + w * 8 + (l >> 3)) * IN_DIM + scol;
    const bf16* gBs = Bw + (size_t)(n0 + w * 8 + (l >> 3)) * IN_DIM + scol;

#define STAGEH(gbase, kc, dstOff) do {                                        \
        gload16((gbase) + (kc),                                               \
                (bf16*)(smem + (dstOff) + (w << 10)));                        \
        gload16((gbase) + (kc) + (size_t)64 * IN_DIM,                         \
                (bf16*)(smem + (dstOff) + 8192 + (w << 10)));                 \
    } while (0)

    // ---- ds_read slot offsets: slot(ks) = (ks*4 + (l>>4)) ^ (l&7).
    const int fr  = l & 15;
    const int sA0 = (((l >> 4) & 3) ^ (l & 7)) << 4;
    const int sA1 = ((4 | ((l >> 4) & 3)) ^ (l & 7)) << 4;
    const char* aB = smem + wm * 8192 + fr * 128;            // + po + QM*16384
    const char* bB = smem + 32768 + wn * 4096 + fr * 128;    // + po + QN*16384

    f32x4 acc[2][2][4][2] = {};
    bf16x8 aF[4][2], bF[2][2];

    // ---- prologue: tile0's 4 halves + tile1's {A-h0, A-h1, B-h1} -> q.
    // vmcnt(6) drains tile0; keeps tile1's 3 halves in flight (= steady-
    // state invariant; ph1(0) stages the missing B-h0(1)).
    STAGEH(gAs, 0, 0);                                   // A-h0(0) -> p
    STAGEH(gBs, 0, 32768);                               // B-h0(0) -> p
    STAGEH(gBs + (size_t)128 * IN_DIM, 0, 49152);        // B-h1(0) -> p
    STAGEH(gAs + (size_t)128 * IN_DIM, 0, 16384);        // A-h1(0) -> p
    STAGEH(gAs, BK, 65536 + 0);                          // A-h0(1) -> q
    STAGEH(gAs + (size_t)128 * IN_DIM, BK, 65536 + 16384);   // A-h1(1) -> q
    STAGEH(gBs + (size_t)128 * IN_DIM, BK, 65536 + 49152);   // B-h1(1) -> q
    WAIT_VM(6);
    BARRIER();

#pragma unroll 2
    for (int kt = 0; kt < 64; ++kt) {
        const int po  = (kt & 1) << 16;
        const int qo  = po ^ 65536;
        const int kc1 = (kt + 1 < 64) ? (kt + 1) * BK : 0;   // clamped
        const int kc2 = (kt + 2 < 64) ? (kt + 2) * BK : 0;   // clamped

        // ===== phase 1: quadrant (0,0) =====
        load_af(aF, aB, po, sA0, sA1);
        load_bf(bF, bB, po, sA0, sA1);
        STAGEH(gBs, kc1, qo + 32768);                    // B-h0(t+1) -> q
        __builtin_amdgcn_s_setprio(1);
        mfma_quad<0, 0>(acc, aF, bF);
        __builtin_amdgcn_s_setprio(0);
        BARRIER();

        // ===== phase 2: quadrant (0,1) — A-frags reused =====
        load_bf(bF, bB, po + 16384, sA0, sA1);
        STAGEH(gAs, kc2, po + 0);                        // A-h0(t+2) -> p
        __builtin_amdgcn_s_setprio(1);
        mfma_quad<0, 1>(acc, aF, bF);
        __builtin_amdgcn_s_setprio(0);
        BARRIER();

        // ===== phase 3: quadrant (1,1) — B-frags reused, no stage =====
        load_af(aF, aB, po + 16384, sA0, sA1);
        __builtin_amdgcn_s_setprio(1);
        mfma_quad<1, 1>(acc, aF, bF);
        __builtin_amdgcn_s_setprio(0);
        BARRIER();

        // ===== phase 4: quadrant (1,0) — B-h0 re-read + 2 stages =====
        load_bf(bF, bB, po, sA0, sA1);
        STAGEH(gAs + (size_t)128 * IN_DIM, kc2, po + 16384);   // A-h1(t+2) -> p
        STAGEH(gBs + (size_t)128 * IN_DIM, kc2, po + 49152);   // B-h1(t+2) -> p
        __builtin_amdgcn_s_setprio(1);
        mfma_quad<1, 0>(acc, aF, bF);
        __builtin_amdgcn_s_setprio(0);
        WAIT_VM(6);        // ONE counted wait per K-tile: drains all of t+1,
        BARRIER();         // keeps {A-h0,A-h1,B-h1}(t+2) (3 STAGEHs) in flight
    }

    // ---- epilogue: drain, then per-wave LDS transpose (stride 33) ----
    asm volatile("s_waitcnt vmcnt(0) lgkmcnt(0)" ::: "memory");
    BARRIER();
    float* sE = (float*)(void*)smem + w * (64 * 33);   // 8448B/wave * 8 = 67.6KB
    const int er = l >> 4;        // 0..3
    const int ec = l & 15;
#pragma unroll
    for (int QM = 0; QM < 2; ++QM)
#pragma unroll
        for (int QN = 0; QN < 2; ++QN) {
            // C/D layout (m89/m91): col = l&15, row = (l>>4)*4 + j
#pragma unroll
            for (int r = 0; r < 4; ++r)
#pragma unroll
                for (int n = 0; n < 2; ++n)
#pragma unroll
                    for (int j = 0; j < 4; ++j)
                        sE[(r * 16 + er * 4 + j) * 33 + n * 16 + ec] =
                            acc[QM][QN][r][n][j];
#pragma unroll
            for (int q = 0; q < 8; ++q) {
                int r2 = q * 8 + (l >> 3);
                int c2 = (l & 7) * 4;
                f32x4 v = { sE[r2 * 33 + c2],     sE[r2 * 33 + c2 + 1],
                            sE[r2 * 33 + c2 + 2], sE[r2 * 33 + c2 + 3] };
                *(f32x4*)(C + (size_t)(m0 + QM * 128 + wm * 64 + r2) * OUT_DIM
                            + (n0 + QN * 128 + wn * 32 + c2)) = v;
            }
        }
}

// -------------------------------------------------------------------------
extern "C" void kernel_launch(void* const* d_in, const int* in_sizes, int n_in,
                              void* d_out, int out_size, void* d_ws, size_t ws_size,
                              hipStream_t stream) {
    (void)in_sizes; (void)n_in; (void)out_size; (void)ws_size;
    const float* x        = (const float*)d_in[0];
    const float* weight   = (const float*)d_in[1];
    const float* scale_A  = (const float*)d_in[2];
    const float* scale_B  = (const float*)d_in[3];
    const float* g        = (const float*)d_in[4];
    const float* lora_A   = (const float*)d_in[5];
    const float* lora_B   = (const float*)d_in[6];
    float* out = (float*)d_out;

    bf16* xb = (bf16*)d_ws;
    bf16* wt = (bf16*)((char*)d_ws + (size_t)M_DIM * IN_DIM * sizeof(bf16));

    prep_fused<<<4096, 256, 0, stream>>>(weight, scale_A, scale_B, g,
                                         lora_A, lora_B, x, wt, xb);

    gemm_bt<<<(M_DIM / BM) * (OUT_DIM / BN), 512, 0, stream>>>(xb, wt, out);
}